// Round 11
// baseline (254.280 us; speedup 1.0000x reference)
//
#include <hip/hip_runtime.h>

// ---------------------------------------------------------------------------
// SympleAgent Tree-LSTM on MI355X — R11: R10 sweepA + single-wave sweepB.
// sweepB (L2..L0 + head) now runs one wave per batch: wave-synchronous (no
// barrier cost), VALU dot-products against a transposed fp32 U table (Ut),
// LDS broadcast for child h. Measured grid-128 4-wave levels cost ~8 us each
// (R8->R9 delta); single-wave chain is ~2-3 us for all of L2..L0+head.
// ---------------------------------------------------------------------------

typedef unsigned short u16;
typedef unsigned int   u32;
typedef __attribute__((ext_vector_type(8))) short  short8;   // 8 bf16
typedef __attribute__((ext_vector_type(4))) float  floatx4;  // MFMA C/D frag

#define L2E  1.44269504f
#define L2E2 2.885390082f

__device__ __forceinline__ float frcp(float x) { return __fdividef(1.0f, x); }
__device__ __forceinline__ float fsig(float x) { return frcp(1.0f + __expf(-x)); }
__device__ __forceinline__ float ftanh(float x) {
    return 1.0f - 2.0f * frcp(__expf(2.0f * x) + 1.0f);
}
__device__ __forceinline__ u16 f2bfa(float x) {  // round-to-nearest
    return (u16)((__float_as_uint(x) + 0x8000u) >> 16);
}
__device__ __forceinline__ float bflo(u32 cc) { return __uint_as_float(cc << 16); }
__device__ __forceinline__ float bfhi(u32 cc) { return __uint_as_float(cc & 0xFFFF0000u); }
__device__ __forceinline__ float bf2f(u16 s) { return __uint_as_float(((u32)s) << 16); }

// LSTM gates on log2e-PRESCALED pre-activations (zu by 2log2e): 6 raw
// v_exp_f32 + 3 v_rcp_f32. Clamps keep garbage/overflow at correct limits.
__device__ __forceinline__ void lstm_gates(
    float zi, float zfa, float zfb, float zo, float zu,
    float ca, float cb, float& c, float& h)
{
    zi  = fmaxf(zi, -60.f);  zfa = fmaxf(zfa, -60.f);
    zfb = fmaxf(zfb, -60.f); zo  = fmaxf(zo, -60.f);
    zu  = fmaxf(zu, -60.f);
    float ei  = __builtin_amdgcn_exp2f(-zi);
    float efa = __builtin_amdgcn_exp2f(-zfa);
    float efb = __builtin_amdgcn_exp2f(-zfb);
    float eo  = __builtin_amdgcn_exp2f(-zo);
    float eu2 = __builtin_amdgcn_exp2f(-zu);
    float pfa = 1.f + efa, pfb = 1.f + efb;
    float cf = (ca * pfb + cb * pfa) * __builtin_amdgcn_rcpf(pfa * pfb);
    c = (1.f - eu2) * __builtin_amdgcn_rcpf((1.f + ei) * (1.f + eu2)) + cf;
    float ec2 = __builtin_amdgcn_exp2f(fminf(-c * L2E2, 80.f));
    h = (1.f - ec2) * __builtin_amdgcn_rcpf((1.f + eo) * (1.f + ec2));
}

#define HS 72   // h LDS row stride (u16): 144 B = 16B-aligned, 2-way banks

// ---------------- precompute: scaled fp32 tables + scaled bf16 U + Ut ------
// Ut[c][k] (320x128 fp32) = U[k][c] * (c in u-gate ? 2log2e : log2e),
// U = vstack(Ua,Ub). Used by the single-wave sweepB dot levels.
__global__ void precompute_kernel(
    const float* __restrict__ Wx, const float* __restrict__ b_tree,
    const float* __restrict__ Ua, const float* __restrict__ Ub,
    float4* __restrict__ WpA, float* __restrict__ WpU,
    float4* __restrict__ TaA, float2* __restrict__ TaUC,
    float4* __restrict__ TbA, float2* __restrict__ TbUC,
    u16* __restrict__ Uswz, float* __restrict__ Ut)
{
    int v = blockIdx.x;
    int t = threadIdx.x;
    __shared__ float sz[320], sta[320], stb[320], sh[64], sc[64];
    float z = Wx[v * 320 + t] + b_tree[t];
    sz[t] = z;
    {   // Uswz: one element per thread (128*320 total)
        int f = v * 320 + t;
        int j = f & 7, lane = (f >> 3) & 63, tk = f >> 9;
        int nt = tk % 20, kc = tk / 20;
        int k = kc * 32 + (lane >> 4) * 8 + j;
        int nn = nt * 16 + (lane & 15);
        float uval = (k < 64) ? Ua[k * 320 + nn] : Ub[(k - 64) * 320 + nn];
        uval *= ((nn >> 6) == 4) ? L2E2 : L2E;
        Uswz[f] = (u16)((__float_as_uint(uval) + 0x7FFFu +
                         ((__float_as_uint(uval) >> 16) & 1u)) >> 16);
    }
    {   // Ut: one element per thread (320*128 total)
        int idx = v * 320 + t;
        int c = idx >> 7, k = idx & 127;
        float uval = (k < 64) ? Ua[k * 320 + c] : Ub[(k - 64) * 320 + c];
        Ut[idx] = uval * (((c >> 6) == 4) ? L2E2 : L2E);
    }
    __syncthreads();
    if (t < 64) {
        float c = fsig(sz[t]) * ftanh(sz[256 + t]);
        float h = fsig(sz[192 + t]) * ftanh(c);
        sc[t] = c; sh[t] = h;
    }
    __syncthreads();
    float ta = 0.f, tb = 0.f;
    #pragma unroll 8
    for (int k = 0; k < 64; ++k) {
        ta += sh[k] * Ua[k * 320 + t];
        tb += sh[k] * Ub[k * 320 + t];
    }
    sta[t] = ta; stb[t] = tb;
    __syncthreads();
    if (t < 64) {
        int o = (v << 6) + t;
        WpA[o]  = make_float4(sz[t] * L2E, sz[64 + t] * L2E,
                              sz[128 + t] * L2E, sz[192 + t] * L2E);
        WpU[o]  = sz[256 + t] * L2E2;
        TaA[o]  = make_float4(sta[t] * L2E, sta[64 + t] * L2E,
                              sta[128 + t] * L2E, sta[192 + t] * L2E);
        TaUC[o] = make_float2(sta[256 + t] * L2E2, sc[t]);
        TbA[o]  = make_float4(stb[t] * L2E, stb[64 + t] * L2E,
                              stb[128 + t] * L2E, stb[192 + t] * L2E);
        TbUC[o] = make_float2(stb[256 + t] * L2E2, sc[t]);
    }
}

// ---------------- one level call: NT 16-row tiles, MFMA + gate epilogue ----
template<int NT, int MODE, int GSRC>
__device__ __forceinline__ void sweep_level(
    const u16* hsrc, const u32* csrc,
    u16* hdst, u16* cdst, u16* hg, u16* cg, float* hroot,
    const short8 Bfrag[4][5],
    const float4* __restrict__ WpA, const float* __restrict__ WpU,
    const int* ids, int lbase, int node0g, int nvalid,
    int lane15, int quad, int wg)
{
    floatx4 acc[NT][5];
    #pragma unroll
    for (int mt = 0; mt < NT; ++mt)
        #pragma unroll
        for (int g = 0; g < 5; ++g) acc[mt][g] = (floatx4){0.f, 0.f, 0.f, 0.f};

    #pragma unroll
    for (int mt = 0; mt < NT; ++mt) {
        #pragma unroll
        for (int kc = 0; kc < 4; ++kc) {
            int child = 2 * (lbase + mt * 16 + lane15) + (kc >> 1);
            const u16* ap = GSRC ? (hsrc + child * 64 + (kc & 1) * 32 + quad * 8)
                                 : (hsrc + child * HS + (kc & 1) * 32 + quad * 8);
            short8 a = *(const short8*)ap;
            #pragma unroll
            for (int g = 0; g < 5; ++g)
                acc[mt][g] = __builtin_amdgcn_mfma_f32_16x16x32_bf16(
                    a, Bfrag[kc][g], acc[mt][g], 0, 0, 0);
        }
    }
    int hh = wg * 16 + lane15;
    #pragma unroll
    for (int mt = 0; mt < NT; ++mt) {
        #pragma unroll
        for (int r = 0; r < 4; ++r) {
            int lrow = lbase + mt * 16 + quad * 4 + r;
            int id = ids[lrow];
            float4 wgv = WpA[(id << 6) + hh];
            float  wu  = WpU[(id << 6) + hh];
            u32 cc = csrc[lrow * 64 + hh];   // children c pair of parent lrow
            float c, h;
            lstm_gates(acc[mt][0][r] + wgv.x, acc[mt][1][r] + wgv.y,
                       acc[mt][2][r] + wgv.z, acc[mt][3][r] + wgv.w,
                       acc[mt][4][r] + wu, bflo(cc), bfhi(cc), c, h);
            if (MODE == 0) {
                hdst[lrow * HS + hh] = f2bfa(h);
                cdst[(lrow >> 1) * 128 + hh * 2 + (lrow & 1)] = f2bfa(c);
            }
            if (MODE == 1) {
                if (lrow < nvalid) {
                    int node = node0g + lrow;
                    hg[node * 64 + hh] = f2bfa(h);
                    cg[(node >> 1) * 128 + hh * 2 + (node & 1)] = f2bfa(c);
                }
            }
            if (MODE == 2) {
                if (lrow == 0) hroot[hh] = h;
            }
        }
    }
}

__device__ __forceinline__ void load_bfrags(short8 Bfrag[4][5],
                                            const u16* __restrict__ Uswz,
                                            int wg, int lane)
{
    #pragma unroll
    for (int kc = 0; kc < 4; ++kc)
        #pragma unroll
        for (int g = 0; g < 5; ++g) {
            int nt = g * 4 + wg;
            Bfrag[kc][g] = *(const short8*)(Uswz + ((kc * 20 + nt) * 64 + lane) * 8);
        }
}

// ---------------- phase A: L10..L3, grid 1024 x 512 threads ----------------
__global__ __launch_bounds__(512, 2) void sweepA_kernel(
    const int* __restrict__ x_idx,
    const float4* __restrict__ WpA, const float* __restrict__ WpU,
    const float4* __restrict__ TaA, const float2* __restrict__ TaUC,
    const float4* __restrict__ TbA, const float2* __restrict__ TbUC,
    const u16* __restrict__ Uswz,
    u16* __restrict__ h3, u16* __restrict__ c3)
{
    __shared__ u16 hA[128 * HS];     // 18432 B
    __shared__ u16 cA[64 * 128];     // 16384 B (paired bf16)
    __shared__ u16 hB[64 * HS];      // 9216 B
    __shared__ u16 cB[32 * 128];     // 8192 B
    __shared__ int sIds[544];        // 511 ids + zero pad
    int t = threadIdx.x, lane = t & 63, wv = t >> 6;
    int wg = wv & 3, wm = wv >> 2;
    int lane15 = lane & 15, quad = lane >> 4;
    int b = blockIdx.x >> 3, st = blockIdx.x & 7;
    const int* xb = x_idx + b * 4095;

    // ---- stage this subtree's ids (coalesced), zero-fill the pad
    for (int i = t; i < 544; i += 512) {
        int g;
        if      (i < 128) g = 1023 + st * 128 + i;              // L10
        else if (i < 384) g = 2047 + st * 256 + (i - 128);      // leaves
        else if (i < 448) g = 511 + st * 64 + (i - 384);        // L9
        else if (i < 480) g = 255 + st * 32 + (i - 448);        // L8
        else if (i < 496) g = 127 + st * 16 + (i - 480);        // L7
        else if (i < 504) g = 63 + st * 8 + (i - 496);          // L6
        else if (i < 508) g = 31 + st * 4 + (i - 504);          // L5
        else if (i < 510) g = 15 + st * 2 + (i - 508);          // L4
        else if (i == 510) g = 7 + st;                          // L3
        else g = -1;
        sIds[i] = (g >= 0) ? xb[g] : 0;
    }
    __syncthreads();

    // ---- L10: 16 rows per wave (8 waves x 16 = 128), lane = hidden col
    #pragma unroll 4
    for (int rr = 0; rr < 16; ++rr) {
        int rl = wv * 16 + rr;
        int id = sIds[rl], ida = sIds[128 + 2 * rl], idb = sIds[129 + 2 * rl];
        float4 wgv = WpA[(id << 6) + lane];  float  wu = WpU[(id << 6) + lane];
        float4 ga = TaA[(ida << 6) + lane];  float2 ua = TaUC[(ida << 6) + lane];
        float4 gb = TbA[(idb << 6) + lane];  float2 ub = TbUC[(idb << 6) + lane];
        float c, h;
        lstm_gates(wgv.x + ga.x + gb.x, wgv.y + ga.y + gb.y, wgv.z + ga.z + gb.z,
                   wgv.w + ga.w + gb.w, wu + ua.x + ub.x, ua.y, ub.y, c, h);
        hA[rl * HS + lane] = f2bfa(h);
        cA[(rl >> 1) * 128 + lane * 2 + (rl & 1)] = f2bfa(c);
    }
    short8 Bfrag[4][5];
    load_bfrags(Bfrag, Uswz, wg, lane);
    __syncthreads();
    // ---- L9: 64 rows = 4 tiles; m-half wm does tiles [wm*2, wm*2+2)
    sweep_level<2, 0, 0>(hA, (const u32*)cA, hB, cB, nullptr, nullptr, nullptr,
                         Bfrag, WpA, WpU, &sIds[384], wm * 32, 0, 64, lane15, quad, wg);
    __syncthreads();
    // ---- L8: 32 rows = 2 tiles; m-half wm does tile wm
    sweep_level<1, 0, 0>(hB, (const u32*)cB, hA, cA, nullptr, nullptr, nullptr,
                         Bfrag, WpA, WpU, &sIds[448], wm * 16, 0, 32, lane15, quad, wg);
    __syncthreads();
    // ---- L7..L3: single tile; wm=0 group only (all waves hit barriers)
    if (wm == 0)
        sweep_level<1, 0, 0>(hA, (const u32*)cA, hB, cB, nullptr, nullptr, nullptr,
                             Bfrag, WpA, WpU, &sIds[480], 0, 0, 16, lane15, quad, wg);
    __syncthreads();
    if (wm == 0)   // L6: 8 valid
        sweep_level<1, 0, 0>(hB, (const u32*)cB, hA, cA, nullptr, nullptr, nullptr,
                             Bfrag, WpA, WpU, &sIds[496], 0, 0, 8, lane15, quad, wg);
    __syncthreads();
    if (wm == 0)   // L5: 4 valid
        sweep_level<1, 0, 0>(hA, (const u32*)cA, hB, cB, nullptr, nullptr, nullptr,
                             Bfrag, WpA, WpU, &sIds[504], 0, 0, 4, lane15, quad, wg);
    __syncthreads();
    if (wm == 0)   // L4: 2 valid
        sweep_level<1, 0, 0>(hB, (const u32*)cB, hA, cA, nullptr, nullptr, nullptr,
                             Bfrag, WpA, WpU, &sIds[508], 0, 0, 2, lane15, quad, wg);
    __syncthreads();
    if (wm == 0)   // L3: 1 valid row -> global (batch-local node st)
        sweep_level<1, 1, 0>(hA, (const u32*)cA, nullptr, nullptr,
                             h3 + (size_t)b * 512, c3 + (size_t)b * 512, nullptr,
                             Bfrag, WpA, WpU, &sIds[510], 0, st, 1, lane15, quad, wg);
}

// ---------------- phase B: L2..L0 + head, ONE WAVE per batch ---------------
// grid 128 x 64. Lane = hidden col. Levels are fp32 dot-products against Ut
// (5 contiguous float4 streams/lane, L1-resident) + LDS broadcast child h.
__global__ __launch_bounds__(64) void sweepB_kernel(
    const int* __restrict__ x_idx,
    const float4* __restrict__ WpA, const float* __restrict__ WpU,
    const float* __restrict__ Ut,
    const u16* __restrict__ h3, const u16* __restrict__ c3,
    const float* __restrict__ W1, const float* __restrict__ b1,
    const float* __restrict__ W2, const float* __restrict__ b2,
    const float* __restrict__ W_ih, const float* __restrict__ b_lstm,
    const float* __restrict__ actor_W, const float* __restrict__ actor_b,
    const float* __restrict__ vm, float* __restrict__ out)
{
    __shared__ float shA[8 * 64], scA[8 * 64];
    __shared__ float shB[8 * 64], scB[8 * 64];
    int lane = threadIdx.x;
    int b = blockIdx.x;
    const int* xb = x_idx + b * 4095;
    const u16* h3b = h3 + (size_t)b * 512;
    const u16* c3b = c3 + (size_t)b * 512;

    // stage L3 state: 8 rows h + c (decode paired bf16)
    #pragma unroll
    for (int n = 0; n < 8; ++n) {
        shA[n * 64 + lane] = bf2f(h3b[n * 64 + lane]);
        scA[n * 64 + lane] = bf2f(c3b[(n >> 1) * 128 + lane * 2 + (n & 1)]);
    }
    const float* u0 = Ut + (0 * 64 + lane) * 128;
    const float* u1 = Ut + (1 * 64 + lane) * 128;
    const float* u2 = Ut + (2 * 64 + lane) * 128;
    const float* u3 = Ut + (3 * 64 + lane) * 128;
    const float* u4 = Ut + (4 * 64 + lane) * 128;
    __syncthreads();

    float* srch = shA; float* srcc = scA;
    float* dsth = shB; float* dstc = scB;
    float hrootv = 0.f;
    #pragma unroll
    for (int lvl = 2; lvl >= 0; --lvl) {
        int nrows = 1 << lvl;              // 4, 2, 1
        int off = nrows - 1;               // level-node base in x_idx
        for (int r = 0; r < nrows; ++r) {
            int id = xb[off + r];
            float4 wgv = WpA[(id << 6) + lane];
            float  wu  = WpU[(id << 6) + lane];
            float zi = wgv.x, zfa = wgv.y, zfb = wgv.z, zo = wgv.w, zu = wu;
            const float* hl = srch + (2 * r) * 64;
            const float* hrr = srch + (2 * r + 1) * 64;
            #pragma unroll
            for (int k = 0; k < 64; k += 4) {
                float4 a0 = *(const float4*)(u0 + k);
                float4 a1 = *(const float4*)(u1 + k);
                float4 a2 = *(const float4*)(u2 + k);
                float4 a3 = *(const float4*)(u3 + k);
                float4 a4 = *(const float4*)(u4 + k);
                float h0 = hl[k], h1 = hl[k + 1], h2 = hl[k + 2], h3v = hl[k + 3];
                zi  += a0.x * h0 + a0.y * h1 + a0.z * h2 + a0.w * h3v;
                zfa += a1.x * h0 + a1.y * h1 + a1.z * h2 + a1.w * h3v;
                zfb += a2.x * h0 + a2.y * h1 + a2.z * h2 + a2.w * h3v;
                zo  += a3.x * h0 + a3.y * h1 + a3.z * h2 + a3.w * h3v;
                zu  += a4.x * h0 + a4.y * h1 + a4.z * h2 + a4.w * h3v;
            }
            #pragma unroll
            for (int k = 0; k < 64; k += 4) {
                float4 a0 = *(const float4*)(u0 + 64 + k);
                float4 a1 = *(const float4*)(u1 + 64 + k);
                float4 a2 = *(const float4*)(u2 + 64 + k);
                float4 a3 = *(const float4*)(u3 + 64 + k);
                float4 a4 = *(const float4*)(u4 + 64 + k);
                float h0 = hrr[k], h1 = hrr[k + 1], h2 = hrr[k + 2], h3v = hrr[k + 3];
                zi  += a0.x * h0 + a0.y * h1 + a0.z * h2 + a0.w * h3v;
                zfa += a1.x * h0 + a1.y * h1 + a1.z * h2 + a1.w * h3v;
                zfb += a2.x * h0 + a2.y * h1 + a2.z * h2 + a2.w * h3v;
                zo  += a3.x * h0 + a3.y * h1 + a3.z * h2 + a3.w * h3v;
                zu  += a4.x * h0 + a4.y * h1 + a4.z * h2 + a4.w * h3v;
            }
            float c, h;
            lstm_gates(zi, zfa, zfb, zo, zu,
                       srcc[(2 * r) * 64 + lane], srcc[(2 * r + 1) * 64 + lane],
                       c, h);
            if (lvl == 0) hrootv = h;
            else { dsth[r * 64 + lane] = h; dstc[r * 64 + lane] = c; }
        }
        __syncthreads();   // single wave: compiles to a cheap waitcnt/barrier
        float* tmp;
        tmp = srch; srch = dsth; dsth = tmp;
        tmp = srcc; srcc = dstc; dstc = tmp;
    }

    // ---- head on the same wave; hroot lives in registers (shuffle access)
    {
        float a = b1[lane];
        #pragma unroll 8
        for (int k = 0; k < 64; ++k) a += __shfl(hrootv, k) * W1[k * 64 + lane];
        float r1 = fmaxf(a, 0.f);
        float f = b2[lane];
        #pragma unroll 8
        for (int k = 0; k < 64; ++k) f += __shfl(r1, k) * W2[k * 64 + lane];
        float gi = b_lstm[lane], gg = b_lstm[128 + lane], go = b_lstm[192 + lane];
        #pragma unroll 8
        for (int k = 0; k < 64; ++k) {
            float fk = __shfl(f, k);
            gi += fk * W_ih[k * 256 + lane];
            gg += fk * W_ih[k * 256 + 128 + lane];
            go += fk * W_ih[k * 256 + 192 + lane];
        }
        float cg = fsig(gi) * ftanh(gg);
        float hg = fsig(go) * ftanh(cg);
        int tt = (lane < 20) ? lane : 19;
        float dot = 0.f;
        #pragma unroll 8
        for (int k = 0; k < 64; ++k) {
            float fk = __shfl(f, k), hk = __shfl(hg, k);
            dot += fk * actor_W[k * 20 + tt] + hk * actor_W[(64 + k) * 20 + tt];
        }
        float m = vm[tt];
        float lg = logf(m) + dot * m + actor_b[tt] * m;
        float mx = -1e30f;
        #pragma unroll
        for (int j = 0; j < 20; ++j) mx = fmaxf(mx, __shfl(lg, j));
        float s = 0.f;
        #pragma unroll
        for (int j = 0; j < 20; ++j) s += __expf((__shfl(lg, j) - mx) * (1.0f / 3.0f));
        if (lane < 20) out[b * 20 + lane] = __expf((lg - mx) * (1.0f / 3.0f)) / s;
    }
}

// ---------------------------------------------------------------------------
extern "C" void kernel_launch(void* const* d_in, const int* in_sizes, int n_in,
                              void* d_out, int out_size, void* d_ws, size_t ws_size,
                              hipStream_t stream)
{
    const int*   x_idx   = (const int*)d_in[0];
    const float* vm      = (const float*)d_in[1];
    const float* Wx      = (const float*)d_in[2];
    const float* Ua      = (const float*)d_in[3];
    const float* Ub      = (const float*)d_in[4];
    const float* b_tree  = (const float*)d_in[5];
    const float* W_ih    = (const float*)d_in[6];
    const float* b_lstm  = (const float*)d_in[8];
    const float* W1      = (const float*)d_in[9];
    const float* b1      = (const float*)d_in[10];
    const float* W2      = (const float*)d_in[11];
    const float* b2      = (const float*)d_in[12];
    const float* actor_W = (const float*)d_in[13];
    const float* actor_b = (const float*)d_in[14];
    float* out = (float*)d_out;

    char* ws = (char*)d_ws;
    float4* WpA  = (float4*)ws;  ws += 128 * 64 * 16;
    float4* TaA  = (float4*)ws;  ws += 128 * 64 * 16;
    float4* TbA  = (float4*)ws;  ws += 128 * 64 * 16;
    float2* TaUC = (float2*)ws;  ws += 128 * 64 * 8;
    float2* TbUC = (float2*)ws;  ws += 128 * 64 * 8;
    float*  WpU  = (float*)ws;   ws += 128 * 64 * 4;
    float*  Ut   = (float*)ws;   ws += 320 * 128 * 4;
    u16*    h3   = (u16*)ws;     ws += 128 * 512 * 2;   // 8 L3 rows / batch
    u16*    c3   = (u16*)ws;     ws += 128 * 512 * 2;   // paired bf16
    u16*    Uswz = (u16*)ws;     ws += 128 * 320 * 2;

    precompute_kernel<<<128, 320, 0, stream>>>(Wx, b_tree, Ua, Ub,
                                               WpA, WpU, TaA, TaUC, TbA, TbUC,
                                               Uswz, Ut);
    sweepA_kernel<<<1024, 512, 0, stream>>>(x_idx, WpA, WpU, TaA, TaUC,
                                            TbA, TbUC, Uswz, h3, c3);
    sweepB_kernel<<<128, 64, 0, stream>>>(x_idx, WpA, WpU, Ut, h3, c3,
                                          W1, b1, W2, b2, W_ih, b_lstm,
                                          actor_W, actor_b, vm, out);
}

// Round 12
// 179.392 us; speedup vs baseline: 1.4175x; 1.4175x over previous
//
#include <hip/hip_runtime.h>

// ---------------------------------------------------------------------------
// SympleAgent Tree-LSTM on MI355X — R12: R10 sweepA + coalesced single-wave
// sweepB. R11's sweepB failed because Ut[c][k] made lanes stride 512 B apart
// (uncoalesced: 64 cache lines per load). Fix: Us[k][320] layout -> lane =
// output col reads 64 consecutive dwords per gate; k outer-loop shares the
// 5 U loads across all rows of a level. Child h via LDS broadcast.
// ---------------------------------------------------------------------------

typedef unsigned short u16;
typedef unsigned int   u32;
typedef __attribute__((ext_vector_type(8))) short  short8;   // 8 bf16
typedef __attribute__((ext_vector_type(4))) float  floatx4;  // MFMA C/D frag

#define L2E  1.44269504f
#define L2E2 2.885390082f

__device__ __forceinline__ float frcp(float x) { return __fdividef(1.0f, x); }
__device__ __forceinline__ float fsig(float x) { return frcp(1.0f + __expf(-x)); }
__device__ __forceinline__ float ftanh(float x) {
    return 1.0f - 2.0f * frcp(__expf(2.0f * x) + 1.0f);
}
__device__ __forceinline__ u16 f2bfa(float x) {  // round-to-nearest
    return (u16)((__float_as_uint(x) + 0x8000u) >> 16);
}
__device__ __forceinline__ float bflo(u32 cc) { return __uint_as_float(cc << 16); }
__device__ __forceinline__ float bfhi(u32 cc) { return __uint_as_float(cc & 0xFFFF0000u); }
__device__ __forceinline__ float bf2f(u16 s) { return __uint_as_float(((u32)s) << 16); }

// LSTM gates on log2e-PRESCALED pre-activations (zu by 2log2e): 6 raw
// v_exp_f32 + 3 v_rcp_f32. Clamps keep garbage/overflow at correct limits.
__device__ __forceinline__ void lstm_gates(
    float zi, float zfa, float zfb, float zo, float zu,
    float ca, float cb, float& c, float& h)
{
    zi  = fmaxf(zi, -60.f);  zfa = fmaxf(zfa, -60.f);
    zfb = fmaxf(zfb, -60.f); zo  = fmaxf(zo, -60.f);
    zu  = fmaxf(zu, -60.f);
    float ei  = __builtin_amdgcn_exp2f(-zi);
    float efa = __builtin_amdgcn_exp2f(-zfa);
    float efb = __builtin_amdgcn_exp2f(-zfb);
    float eo  = __builtin_amdgcn_exp2f(-zo);
    float eu2 = __builtin_amdgcn_exp2f(-zu);
    float pfa = 1.f + efa, pfb = 1.f + efb;
    float cf = (ca * pfb + cb * pfa) * __builtin_amdgcn_rcpf(pfa * pfb);
    c = (1.f - eu2) * __builtin_amdgcn_rcpf((1.f + ei) * (1.f + eu2)) + cf;
    float ec2 = __builtin_amdgcn_exp2f(fminf(-c * L2E2, 80.f));
    h = (1.f - ec2) * __builtin_amdgcn_rcpf((1.f + eo) * (1.f + ec2));
}

#define HS 72   // h LDS row stride (u16): 144 B = 16B-aligned, 2-way banks

// ---------------- precompute: scaled fp32 tables + scaled bf16 U + Us ------
// Us[k][c] (128x320 fp32, coalesced for sweepB) = U[k][c] * scale(c),
// scale = 2log2e for the u-gate block (c>=256), else log2e. U = vstack(Ua,Ub).
__global__ void precompute_kernel(
    const float* __restrict__ Wx, const float* __restrict__ b_tree,
    const float* __restrict__ Ua, const float* __restrict__ Ub,
    float4* __restrict__ WpA, float* __restrict__ WpU,
    float4* __restrict__ TaA, float2* __restrict__ TaUC,
    float4* __restrict__ TbA, float2* __restrict__ TbUC,
    u16* __restrict__ Uswz, float* __restrict__ Us)
{
    int v = blockIdx.x;
    int t = threadIdx.x;
    __shared__ float sz[320], sta[320], stb[320], sh[64], sc[64];
    float z = Wx[v * 320 + t] + b_tree[t];
    sz[t] = z;
    {   // Uswz: one element per thread (128*320 total)
        int f = v * 320 + t;
        int j = f & 7, lane = (f >> 3) & 63, tk = f >> 9;
        int nt = tk % 20, kc = tk / 20;
        int k = kc * 32 + (lane >> 4) * 8 + j;
        int nn = nt * 16 + (lane & 15);
        float uval = (k < 64) ? Ua[k * 320 + nn] : Ub[(k - 64) * 320 + nn];
        uval *= ((nn >> 6) == 4) ? L2E2 : L2E;
        Uswz[f] = (u16)((__float_as_uint(uval) + 0x7FFFu +
                         ((__float_as_uint(uval) >> 16) & 1u)) >> 16);
    }
    {   // Us: row k = v, col = t (coalesced [k][320] layout)
        float uval = (v < 64) ? Ua[v * 320 + t] : Ub[(v - 64) * 320 + t];
        Us[v * 320 + t] = uval * ((t >= 256) ? L2E2 : L2E);
    }
    __syncthreads();
    if (t < 64) {
        float c = fsig(sz[t]) * ftanh(sz[256 + t]);
        float h = fsig(sz[192 + t]) * ftanh(c);
        sc[t] = c; sh[t] = h;
    }
    __syncthreads();
    float ta = 0.f, tb = 0.f;
    #pragma unroll 8
    for (int k = 0; k < 64; ++k) {
        ta += sh[k] * Ua[k * 320 + t];
        tb += sh[k] * Ub[k * 320 + t];
    }
    sta[t] = ta; stb[t] = tb;
    __syncthreads();
    if (t < 64) {
        int o = (v << 6) + t;
        WpA[o]  = make_float4(sz[t] * L2E, sz[64 + t] * L2E,
                              sz[128 + t] * L2E, sz[192 + t] * L2E);
        WpU[o]  = sz[256 + t] * L2E2;
        TaA[o]  = make_float4(sta[t] * L2E, sta[64 + t] * L2E,
                              sta[128 + t] * L2E, sta[192 + t] * L2E);
        TaUC[o] = make_float2(sta[256 + t] * L2E2, sc[t]);
        TbA[o]  = make_float4(stb[t] * L2E, stb[64 + t] * L2E,
                              stb[128 + t] * L2E, stb[192 + t] * L2E);
        TbUC[o] = make_float2(stb[256 + t] * L2E2, sc[t]);
    }
}

// ---------------- one level call: NT 16-row tiles, MFMA + gate epilogue ----
template<int NT, int MODE, int GSRC>
__device__ __forceinline__ void sweep_level(
    const u16* hsrc, const u32* csrc,
    u16* hdst, u16* cdst, u16* hg, u16* cg, float* hroot,
    const short8 Bfrag[4][5],
    const float4* __restrict__ WpA, const float* __restrict__ WpU,
    const int* ids, int lbase, int node0g, int nvalid,
    int lane15, int quad, int wg)
{
    floatx4 acc[NT][5];
    #pragma unroll
    for (int mt = 0; mt < NT; ++mt)
        #pragma unroll
        for (int g = 0; g < 5; ++g) acc[mt][g] = (floatx4){0.f, 0.f, 0.f, 0.f};

    #pragma unroll
    for (int mt = 0; mt < NT; ++mt) {
        #pragma unroll
        for (int kc = 0; kc < 4; ++kc) {
            int child = 2 * (lbase + mt * 16 + lane15) + (kc >> 1);
            const u16* ap = GSRC ? (hsrc + child * 64 + (kc & 1) * 32 + quad * 8)
                                 : (hsrc + child * HS + (kc & 1) * 32 + quad * 8);
            short8 a = *(const short8*)ap;
            #pragma unroll
            for (int g = 0; g < 5; ++g)
                acc[mt][g] = __builtin_amdgcn_mfma_f32_16x16x32_bf16(
                    a, Bfrag[kc][g], acc[mt][g], 0, 0, 0);
        }
    }
    int hh = wg * 16 + lane15;
    #pragma unroll
    for (int mt = 0; mt < NT; ++mt) {
        #pragma unroll
        for (int r = 0; r < 4; ++r) {
            int lrow = lbase + mt * 16 + quad * 4 + r;
            int id = ids[lrow];
            float4 wgv = WpA[(id << 6) + hh];
            float  wu  = WpU[(id << 6) + hh];
            u32 cc = csrc[lrow * 64 + hh];   // children c pair of parent lrow
            float c, h;
            lstm_gates(acc[mt][0][r] + wgv.x, acc[mt][1][r] + wgv.y,
                       acc[mt][2][r] + wgv.z, acc[mt][3][r] + wgv.w,
                       acc[mt][4][r] + wu, bflo(cc), bfhi(cc), c, h);
            if (MODE == 0) {
                hdst[lrow * HS + hh] = f2bfa(h);
                cdst[(lrow >> 1) * 128 + hh * 2 + (lrow & 1)] = f2bfa(c);
            }
            if (MODE == 1) {
                if (lrow < nvalid) {
                    int node = node0g + lrow;
                    hg[node * 64 + hh] = f2bfa(h);
                    cg[(node >> 1) * 128 + hh * 2 + (node & 1)] = f2bfa(c);
                }
            }
            if (MODE == 2) {
                if (lrow == 0) hroot[hh] = h;
            }
        }
    }
}

__device__ __forceinline__ void load_bfrags(short8 Bfrag[4][5],
                                            const u16* __restrict__ Uswz,
                                            int wg, int lane)
{
    #pragma unroll
    for (int kc = 0; kc < 4; ++kc)
        #pragma unroll
        for (int g = 0; g < 5; ++g) {
            int nt = g * 4 + wg;
            Bfrag[kc][g] = *(const short8*)(Uswz + ((kc * 20 + nt) * 64 + lane) * 8);
        }
}

// ---------------- phase A: L10..L3, grid 1024 x 512 threads ----------------
__global__ __launch_bounds__(512, 2) void sweepA_kernel(
    const int* __restrict__ x_idx,
    const float4* __restrict__ WpA, const float* __restrict__ WpU,
    const float4* __restrict__ TaA, const float2* __restrict__ TaUC,
    const float4* __restrict__ TbA, const float2* __restrict__ TbUC,
    const u16* __restrict__ Uswz,
    u16* __restrict__ h3, u16* __restrict__ c3)
{
    __shared__ u16 hA[128 * HS];     // 18432 B
    __shared__ u16 cA[64 * 128];     // 16384 B (paired bf16)
    __shared__ u16 hB[64 * HS];      // 9216 B
    __shared__ u16 cB[32 * 128];     // 8192 B
    __shared__ int sIds[544];        // 511 ids + zero pad
    int t = threadIdx.x, lane = t & 63, wv = t >> 6;
    int wg = wv & 3, wm = wv >> 2;
    int lane15 = lane & 15, quad = lane >> 4;
    int b = blockIdx.x >> 3, st = blockIdx.x & 7;
    const int* xb = x_idx + b * 4095;

    // ---- stage this subtree's ids (coalesced), zero-fill the pad
    for (int i = t; i < 544; i += 512) {
        int g;
        if      (i < 128) g = 1023 + st * 128 + i;              // L10
        else if (i < 384) g = 2047 + st * 256 + (i - 128);      // leaves
        else if (i < 448) g = 511 + st * 64 + (i - 384);        // L9
        else if (i < 480) g = 255 + st * 32 + (i - 448);        // L8
        else if (i < 496) g = 127 + st * 16 + (i - 480);        // L7
        else if (i < 504) g = 63 + st * 8 + (i - 496);          // L6
        else if (i < 508) g = 31 + st * 4 + (i - 504);          // L5
        else if (i < 510) g = 15 + st * 2 + (i - 508);          // L4
        else if (i == 510) g = 7 + st;                          // L3
        else g = -1;
        sIds[i] = (g >= 0) ? xb[g] : 0;
    }
    __syncthreads();

    // ---- L10: 16 rows per wave (8 waves x 16 = 128), lane = hidden col
    #pragma unroll 4
    for (int rr = 0; rr < 16; ++rr) {
        int rl = wv * 16 + rr;
        int id = sIds[rl], ida = sIds[128 + 2 * rl], idb = sIds[129 + 2 * rl];
        float4 wgv = WpA[(id << 6) + lane];  float  wu = WpU[(id << 6) + lane];
        float4 ga = TaA[(ida << 6) + lane];  float2 ua = TaUC[(ida << 6) + lane];
        float4 gb = TbA[(idb << 6) + lane];  float2 ub = TbUC[(idb << 6) + lane];
        float c, h;
        lstm_gates(wgv.x + ga.x + gb.x, wgv.y + ga.y + gb.y, wgv.z + ga.z + gb.z,
                   wgv.w + ga.w + gb.w, wu + ua.x + ub.x, ua.y, ub.y, c, h);
        hA[rl * HS + lane] = f2bfa(h);
        cA[(rl >> 1) * 128 + lane * 2 + (rl & 1)] = f2bfa(c);
    }
    short8 Bfrag[4][5];
    load_bfrags(Bfrag, Uswz, wg, lane);
    __syncthreads();
    // ---- L9: 64 rows = 4 tiles; m-half wm does tiles [wm*2, wm*2+2)
    sweep_level<2, 0, 0>(hA, (const u32*)cA, hB, cB, nullptr, nullptr, nullptr,
                         Bfrag, WpA, WpU, &sIds[384], wm * 32, 0, 64, lane15, quad, wg);
    __syncthreads();
    // ---- L8: 32 rows = 2 tiles; m-half wm does tile wm
    sweep_level<1, 0, 0>(hB, (const u32*)cB, hA, cA, nullptr, nullptr, nullptr,
                         Bfrag, WpA, WpU, &sIds[448], wm * 16, 0, 32, lane15, quad, wg);
    __syncthreads();
    // ---- L7..L3: single tile; wm=0 group only (all waves hit barriers)
    if (wm == 0)
        sweep_level<1, 0, 0>(hA, (const u32*)cA, hB, cB, nullptr, nullptr, nullptr,
                             Bfrag, WpA, WpU, &sIds[480], 0, 0, 16, lane15, quad, wg);
    __syncthreads();
    if (wm == 0)   // L6: 8 valid
        sweep_level<1, 0, 0>(hB, (const u32*)cB, hA, cA, nullptr, nullptr, nullptr,
                             Bfrag, WpA, WpU, &sIds[496], 0, 0, 8, lane15, quad, wg);
    __syncthreads();
    if (wm == 0)   // L5: 4 valid
        sweep_level<1, 0, 0>(hA, (const u32*)cA, hB, cB, nullptr, nullptr, nullptr,
                             Bfrag, WpA, WpU, &sIds[504], 0, 0, 4, lane15, quad, wg);
    __syncthreads();
    if (wm == 0)   // L4: 2 valid
        sweep_level<1, 0, 0>(hB, (const u32*)cB, hA, cA, nullptr, nullptr, nullptr,
                             Bfrag, WpA, WpU, &sIds[508], 0, 0, 2, lane15, quad, wg);
    __syncthreads();
    if (wm == 0)   // L3: 1 valid row -> global (batch-local node st)
        sweep_level<1, 1, 0>(hA, (const u32*)cA, nullptr, nullptr,
                             h3 + (size_t)b * 512, c3 + (size_t)b * 512, nullptr,
                             Bfrag, WpA, WpU, &sIds[510], 0, st, 1, lane15, quad, wg);
}

// ---------------- sweepB dot level: NR rows, k-outer (U loads shared) ------
template<int NR>
__device__ __forceinline__ void dot_level(
    const float* __restrict__ Us, const float4* __restrict__ WpA,
    const float* __restrict__ WpU, const int* __restrict__ xb,
    const float* srch, const float* srcc,
    float* dsth, float* dstc, float* hrootv, int lane)
{
    int off = NR - 1;
    float z[NR][5];
    #pragma unroll
    for (int r = 0; r < NR; ++r) {
        int id = xb[off + r];
        float4 wgv = WpA[(id << 6) + lane];
        z[r][0] = wgv.x; z[r][1] = wgv.y; z[r][2] = wgv.z; z[r][3] = wgv.w;
        z[r][4] = WpU[(id << 6) + lane];
    }
    #pragma unroll 4
    for (int k = 0; k < 128; ++k) {
        const float* uk = Us + k * 320 + lane;
        float u0 = uk[0], u1 = uk[64], u2 = uk[128], u3 = uk[192], u4 = uk[256];
        #pragma unroll
        for (int r = 0; r < NR; ++r) {
            float hk = srch[(2 * r + (k >> 6)) * 64 + (k & 63)];
            z[r][0] += u0 * hk; z[r][1] += u1 * hk; z[r][2] += u2 * hk;
            z[r][3] += u3 * hk; z[r][4] += u4 * hk;
        }
    }
    #pragma unroll
    for (int r = 0; r < NR; ++r) {
        float c, h;
        lstm_gates(z[r][0], z[r][1], z[r][2], z[r][3], z[r][4],
                   srcc[(2 * r) * 64 + lane], srcc[(2 * r + 1) * 64 + lane], c, h);
        if (NR == 1) *hrootv = h;
        else { dsth[r * 64 + lane] = h; dstc[r * 64 + lane] = c; }
    }
}

// ---------------- phase B: L2..L0 + head, ONE WAVE per batch ---------------
// grid 128 x 64. Lane = hidden col; U loads coalesced (lane-contiguous).
__global__ __launch_bounds__(64) void sweepB_kernel(
    const int* __restrict__ x_idx,
    const float4* __restrict__ WpA, const float* __restrict__ WpU,
    const float* __restrict__ Us,
    const u16* __restrict__ h3, const u16* __restrict__ c3,
    const float* __restrict__ W1, const float* __restrict__ b1,
    const float* __restrict__ W2, const float* __restrict__ b2,
    const float* __restrict__ W_ih, const float* __restrict__ b_lstm,
    const float* __restrict__ actor_W, const float* __restrict__ actor_b,
    const float* __restrict__ vm, float* __restrict__ out)
{
    __shared__ float shA[8 * 64], scA[8 * 64];
    __shared__ float shB[4 * 64], scB[4 * 64];
    int lane = threadIdx.x;
    int b = blockIdx.x;
    const int* xb = x_idx + b * 4095;
    const u16* h3b = h3 + (size_t)b * 512;
    const u16* c3b = c3 + (size_t)b * 512;

    // stage L3 state: 8 rows h + c (decode paired bf16)
    #pragma unroll
    for (int n = 0; n < 8; ++n) {
        shA[n * 64 + lane] = bf2f(h3b[n * 64 + lane]);
        scA[n * 64 + lane] = bf2f(c3b[(n >> 1) * 128 + lane * 2 + (n & 1)]);
    }
    __syncthreads();

    float hrootv = 0.f;
    dot_level<4>(Us, WpA, WpU, xb, shA, scA, shB, scB, nullptr, lane);  // L2
    __syncthreads();
    dot_level<2>(Us, WpA, WpU, xb, shB, scB, shA, scA, nullptr, lane);  // L1
    __syncthreads();
    dot_level<1>(Us, WpA, WpU, xb, shA, scA, nullptr, nullptr, &hrootv, lane); // L0

    // ---- head on the same wave; hroot lives in registers (shuffle access)
    {
        float a = b1[lane];
        #pragma unroll 8
        for (int k = 0; k < 64; ++k) a += __shfl(hrootv, k) * W1[k * 64 + lane];
        float r1 = fmaxf(a, 0.f);
        float f = b2[lane];
        #pragma unroll 8
        for (int k = 0; k < 64; ++k) f += __shfl(r1, k) * W2[k * 64 + lane];
        float gi = b_lstm[lane], gg = b_lstm[128 + lane], go = b_lstm[192 + lane];
        #pragma unroll 8
        for (int k = 0; k < 64; ++k) {
            float fk = __shfl(f, k);
            gi += fk * W_ih[k * 256 + lane];
            gg += fk * W_ih[k * 256 + 128 + lane];
            go += fk * W_ih[k * 256 + 192 + lane];
        }
        float cg = fsig(gi) * ftanh(gg);
        float hg = fsig(go) * ftanh(cg);
        int tt = (lane < 20) ? lane : 19;
        float dot = 0.f;
        #pragma unroll 8
        for (int k = 0; k < 64; ++k) {
            float fk = __shfl(f, k), hk = __shfl(hg, k);
            dot += fk * actor_W[k * 20 + tt] + hk * actor_W[(64 + k) * 20 + tt];
        }
        float m = vm[tt];
        float lg = logf(m) + dot * m + actor_b[tt] * m;
        float mx = -1e30f;
        #pragma unroll
        for (int j = 0; j < 20; ++j) mx = fmaxf(mx, __shfl(lg, j));
        float s = 0.f;
        #pragma unroll
        for (int j = 0; j < 20; ++j) s += __expf((__shfl(lg, j) - mx) * (1.0f / 3.0f));
        if (lane < 20) out[b * 20 + lane] = __expf((lg - mx) * (1.0f / 3.0f)) / s;
    }
}

// ---------------------------------------------------------------------------
extern "C" void kernel_launch(void* const* d_in, const int* in_sizes, int n_in,
                              void* d_out, int out_size, void* d_ws, size_t ws_size,
                              hipStream_t stream)
{
    const int*   x_idx   = (const int*)d_in[0];
    const float* vm      = (const float*)d_in[1];
    const float* Wx      = (const float*)d_in[2];
    const float* Ua      = (const float*)d_in[3];
    const float* Ub      = (const float*)d_in[4];
    const float* b_tree  = (const float*)d_in[5];
    const float* W_ih    = (const float*)d_in[6];
    const float* b_lstm  = (const float*)d_in[8];
    const float* W1      = (const float*)d_in[9];
    const float* b1      = (const float*)d_in[10];
    const float* W2      = (const float*)d_in[11];
    const float* b2      = (const float*)d_in[12];
    const float* actor_W = (const float*)d_in[13];
    const float* actor_b = (const float*)d_in[14];
    float* out = (float*)d_out;

    char* ws = (char*)d_ws;
    float4* WpA  = (float4*)ws;  ws += 128 * 64 * 16;
    float4* TaA  = (float4*)ws;  ws += 128 * 64 * 16;
    float4* TbA  = (float4*)ws;  ws += 128 * 64 * 16;
    float2* TaUC = (float2*)ws;  ws += 128 * 64 * 8;
    float2* TbUC = (float2*)ws;  ws += 128 * 64 * 8;
    float*  WpU  = (float*)ws;   ws += 128 * 64 * 4;
    float*  Us   = (float*)ws;   ws += 128 * 320 * 4;
    u16*    h3   = (u16*)ws;     ws += 128 * 512 * 2;   // 8 L3 rows / batch
    u16*    c3   = (u16*)ws;     ws += 128 * 512 * 2;   // paired bf16
    u16*    Uswz = (u16*)ws;     ws += 128 * 320 * 2;

    precompute_kernel<<<128, 320, 0, stream>>>(Wx, b_tree, Ua, Ub,
                                               WpA, WpU, TaA, TaUC, TbA, TbUC,
                                               Uswz, Us);
    sweepA_kernel<<<1024, 512, 0, stream>>>(x_idx, WpA, WpU, TaA, TaUC,
                                            TbA, TbUC, Uswz, h3, c3);
    sweepB_kernel<<<128, 64, 0, stream>>>(x_idx, WpA, WpU, Us, h3, c3,
                                          W1, b1, W2, b2, W_ih, b_lstm,
                                          actor_W, actor_b, vm, out);
}